// Round 1
// baseline (12336.992 us; speedup 1.0000x reference)
//
#include <hip/hip_runtime.h>
#include <hip/hip_bf16.h>
#include <math.h>

// Problem constants (from reference)
#define BB 256
#define TT 256
// H = [128,32,32], TH=192, ZDIM=64, ATT=4

__device__ __forceinline__ float sigf(float x) { return 1.f / (1.f + expf(-x)); }

// ---------------------------------------------------------------------------
// Kernel 1: G = X @ W + bias   (X: [M,K], W: [K,N], G: [M,N])
// 128x64 tile, 256 threads, 8x4 microtile, TK=16, K-remainder guarded.
// ---------------------------------------------------------------------------
#define GT_M 128
#define GT_N 64
#define GT_K 16

__global__ __launch_bounds__(256)
void xw_gemm(const float* __restrict__ X, const float* __restrict__ W,
             const float* __restrict__ bias, float* __restrict__ G,
             int M, int N, int K) {
    __shared__ float As[GT_K][GT_M + 4];   // +4 pad: 2-way-max bank aliasing
    __shared__ float Bs[GT_K][GT_N];
    const int tid = threadIdx.x;
    const int bm = blockIdx.y * GT_M;
    const int bn = blockIdx.x * GT_N;
    const int tx = tid & 15;    // 16 col groups * 4 cols
    const int ty = tid >> 4;    // 16 row groups * 8 rows

    float acc[8][4];
#pragma unroll
    for (int i = 0; i < 8; ++i)
#pragma unroll
        for (int j = 0; j < 4; ++j) acc[i][j] = 0.f;

    for (int kt = 0; kt < K; kt += GT_K) {
        // stage A-tile: 128x16, 8 elems/thread. thread -> (m = idx>>4, k = idx&15)
#pragma unroll
        for (int i = 0; i < 8; ++i) {
            int idx = i * 256 + tid;
            int m = idx >> 4, k = idx & 15;
            int gk = kt + k;
            As[k][m] = (gk < K) ? X[(size_t)(bm + m) * K + gk] : 0.f;
        }
        // stage B-tile: 16x64, 4 elems/thread. thread -> (k = idx>>6, n = idx&63)
#pragma unroll
        for (int i = 0; i < 4; ++i) {
            int idx = i * 256 + tid;
            int k = idx >> 6, n = idx & 63;
            int gk = kt + k;
            Bs[k][n] = (gk < K) ? W[(size_t)gk * N + bn + n] : 0.f;
        }
        __syncthreads();
#pragma unroll
        for (int k = 0; k < GT_K; ++k) {
            float a[8], b[4];
            const float4 a0 = *(const float4*)&As[k][ty * 8];
            const float4 a1 = *(const float4*)&As[k][ty * 8 + 4];
            const float4 bv = *(const float4*)&Bs[k][tx * 4];
            a[0]=a0.x; a[1]=a0.y; a[2]=a0.z; a[3]=a0.w;
            a[4]=a1.x; a[5]=a1.y; a[6]=a1.z; a[7]=a1.w;
            b[0]=bv.x; b[1]=bv.y; b[2]=bv.z; b[3]=bv.w;
#pragma unroll
            for (int i = 0; i < 8; ++i)
#pragma unroll
                for (int j = 0; j < 4; ++j) acc[i][j] += a[i] * b[j];
        }
        __syncthreads();
    }
    const int n0 = bn + tx * 4;
#pragma unroll
    for (int i = 0; i < 8; ++i) {
        int m = bm + ty * 8 + i;
        float4 v;
        v.x = acc[i][0] + bias[n0 + 0];
        v.y = acc[i][1] + bias[n0 + 1];
        v.z = acc[i][2] + bias[n0 + 2];
        v.w = acc[i][3] + bias[n0 + 3];
        *(float4*)&G[(size_t)m * N + n0] = v;
    }
}

// ---------------------------------------------------------------------------
// Kernel 2: persistent recurrence. 64 blocks x 512 threads.
// Block owns 4 batch rows: two 256-thread halves, each half = 2 rows.
// All carry state in LDS; weights streamed from L2 each step.
// ---------------------------------------------------------------------------
__global__ __launch_bounds__(512)
void marn_rec(const float* __restrict__ G0, const float* __restrict__ G1,
              const float* __restrict__ G2,
              const float* __restrict__ U0, const float* __restrict__ V0,
              const float* __restrict__ U1, const float* __restrict__ V1,
              const float* __restrict__ U2, const float* __restrict__ V2,
              const float* __restrict__ aw1, const float* __restrict__ ab1,
              const float* __restrict__ aw2, const float* __restrict__ ab2,
              const float* __restrict__ cw10, const float* __restrict__ cb10,
              const float* __restrict__ cw20, const float* __restrict__ cb20,
              const float* __restrict__ cw11, const float* __restrict__ cb11,
              const float* __restrict__ cw21, const float* __restrict__ cb21,
              const float* __restrict__ cw12, const float* __restrict__ cb12,
              const float* __restrict__ cw22, const float* __restrict__ cb22,
              const float* __restrict__ fw1, const float* __restrict__ fb1,
              const float* __restrict__ fw2, const float* __restrict__ fb2,
              float* __restrict__ out) {
    // 4 rows per block
    __shared__ float hcat[4][192];   // [h0(128) | h1(32) | h2(32)]
    __shared__ float cst[4][192];    // cell states, same layout
    __shared__ float zz[4][64];
    __shared__ float sbuf[4][768];   // s pre-activations; later reused as att_out
    __shared__ float a1s[4][256];    // attention hidden
    __shared__ float attE[4][768];   // exp(sigmoid(att)) for softmax
    __shared__ float hid[4][128];    // compression hidden [64|32|32]; reused by final MLP
    __shared__ float dex[4][64];     // exp(sigmoid(d)) for z-softmax
    __shared__ float red[4][4];      // per-(row,head) softmax denominators
    __shared__ float zsum[4];

    const int tid = threadIdx.x;
    const int ct  = tid & 255;   // position within half
    const int rp  = tid >> 8;    // which half (row pair)
    const int R0  = rp * 2;
    const int row0 = blockIdx.x * 4;   // global row base for this block

    for (int i = tid; i < 4 * 192; i += 512) { (&hcat[0][0])[i] = 0.f; (&cst[0][0])[i] = 0.f; }
    for (int i = tid; i < 4 * 64; i += 512) (&zz[0][0])[i] = 0.f;
    __syncthreads();

    for (int t = 0; t < TT; ++t) {
        // ---------------- stage A: s = xw + h@U + z@V ----------------
        {
            // cell0: cols ct and ct+256 (K literal for unrolling)
#pragma unroll
            for (int half = 0; half < 2; ++half) {
                const int col = ct + half * 256;
                float acc0 = G0[((size_t)(row0 + R0 + 0) * TT + t) * 512 + col];
                float acc1 = G0[((size_t)(row0 + R0 + 1) * TT + t) * 512 + col];
#pragma unroll 16
                for (int k = 0; k < 128; ++k) {
                    float u = U0[k * 512 + col];
                    acc0 += hcat[R0 + 0][k] * u;
                    acc1 += hcat[R0 + 1][k] * u;
                }
#pragma unroll 16
                for (int k = 0; k < 64; ++k) {
                    float v = V0[k * 512 + col];
                    acc0 += zz[R0 + 0][k] * v;
                    acc1 += zz[R0 + 1][k] * v;
                }
                sbuf[R0 + 0][col] = acc0;
                sbuf[R0 + 1][col] = acc1;
            }
            // cell1 (ct<128) / cell2 (ct>=128): jj = ct+512
            {
                const int jj = ct + 512;
                const float *U, *V, *Gx; int col, hoff;
                if (ct < 128) { col = ct;       U = U1; V = V1; hoff = 128; Gx = G1; }
                else          { col = ct - 128; U = U2; V = V2; hoff = 160; Gx = G2; }
                float acc0 = Gx[((size_t)(row0 + R0 + 0) * TT + t) * 128 + col];
                float acc1 = Gx[((size_t)(row0 + R0 + 1) * TT + t) * 128 + col];
#pragma unroll
                for (int k = 0; k < 32; ++k) {
                    float u = U[k * 128 + col];
                    acc0 += hcat[R0 + 0][hoff + k] * u;
                    acc1 += hcat[R0 + 1][hoff + k] * u;
                }
#pragma unroll 16
                for (int k = 0; k < 64; ++k) {
                    float v = V[k * 128 + col];
                    acc0 += zz[R0 + 0][k] * v;
                    acc1 += zz[R0 + 1][k] * v;
                }
                sbuf[R0 + 0][jj] = acc0;
                sbuf[R0 + 1][jj] = acc1;
            }
        }
        __syncthreads();
        // ---------------- gates -> h, c ----------------
        if (ct < 192) {
            int sb, hd, u;
            if (ct < 128)      { sb = 0;   hd = 128; u = ct; }
            else if (ct < 160) { sb = 512; hd = 32;  u = ct - 128; }
            else               { sb = 640; hd = 32;  u = ct - 160; }
#pragma unroll
            for (int r = 0; r < 2; ++r) {
                const int R = R0 + r;
                float f  = sigf(sbuf[R][sb + u]);
                float ig = sigf(sbuf[R][sb + hd + u]);
                float o  = sigf(sbuf[R][sb + 2 * hd + u]);
                float ch = tanhf(sbuf[R][sb + 3 * hd + u]);
                float c = f * cst[R][ct] + ig * ch;
                cst[R][ct] = c;
                hcat[R][ct] = tanhf(c) * o;
            }
        }
        __syncthreads();
        // ---------------- attention layer 1: relu(hcat@aw1 + ab1) ----------------
        {
            float acc0 = ab1[ct], acc1 = ab1[ct];
#pragma unroll 16
            for (int k = 0; k < 192; ++k) {
                float w = aw1[k * 256 + ct];
                acc0 += hcat[R0 + 0][k] * w;
                acc1 += hcat[R0 + 1][k] * w;
            }
            a1s[R0 + 0][ct] = fmaxf(acc0, 0.f);
            a1s[R0 + 1][ct] = fmaxf(acc1, 0.f);
        }
        __syncthreads();
        // ---------------- attention layer 2 + sigmoid + exp ----------------
#pragma unroll
        for (int it = 0; it < 3; ++it) {
            const int jj = ct + it * 256;
            float acc0 = ab2[jj], acc1 = ab2[jj];
#pragma unroll 16
            for (int k = 0; k < 256; ++k) {
                float w = aw2[k * 768 + jj];
                acc0 += a1s[R0 + 0][k] * w;
                acc1 += a1s[R0 + 1][k] * w;
            }
            attE[R0 + 0][jj] = expf(sigf(acc0));
            attE[R0 + 1][jj] = expf(sigf(acc1));
        }
        __syncthreads();
        // ---------------- per-(row,head) softmax denominators ----------------
        {
            const int p = ct >> 5, l = ct & 31;     // 8 pairs per half
            const int r2 = p >> 2, a = p & 3;
            const int R = R0 + r2;
            float v = 0.f;
            for (int j = l; j < 192; j += 32) v += attE[R][a * 192 + j];
#pragma unroll
            for (int s = 16; s >= 1; s >>= 1) v += __shfl_xor(v, s);
            if (l == 0) red[R][a] = v;
        }
        __syncthreads();
        // ---------------- att_out = softmax(att) * tiled(h) -> sbuf ----------------
#pragma unroll
        for (int it = 0; it < 3; ++it) {
            const int jj = ct + it * 256;
            const int a = jj / 192;
#pragma unroll
            for (int r = 0; r < 2; ++r) {
                const int R = R0 + r;
                float atv = attE[R][jj] / red[R][a];
                float ot = (jj < 512) ? hcat[R][jj & 127]
                         : (jj < 640) ? hcat[R][128 + ((jj - 512) & 31)]
                                      : hcat[R][160 + ((jj - 640) & 31)];
                sbuf[R][jj] = atv * ot;
            }
        }
        __syncthreads();
        // ---------------- compression hidden: relu(att_out@cw1 + cb1) ----------------
        {
            const int col = ct & 127, r2 = ct >> 7;
            const int R = R0 + r2;
            float acc;
            if (col < 64) {
                acc = cb10[col];
                const float* inp = &sbuf[R][0];
#pragma unroll 16
                for (int k = 0; k < 512; ++k) acc += inp[k] * cw10[k * 64 + col];
            } else {
                const float* w; const float* inp; int oc;
                if (col < 96) { w = cw11; inp = &sbuf[R][512]; oc = col - 64; acc = cb11[oc]; }
                else          { w = cw12; inp = &sbuf[R][640]; oc = col - 96; acc = cb12[oc]; }
#pragma unroll 16
                for (int k = 0; k < 128; ++k) acc += inp[k] * w[k * 32 + oc];
            }
            hid[R][col] = fmaxf(acc, 0.f);
        }
        __syncthreads();
        // ---------------- compression out + sigmoid + exp ----------------
        if (ct < 128) {
            const int j = ct & 63, r2 = ct >> 6;
            const int R = R0 + r2;
            float acc;
            if (j < 32) {
                acc = cb20[j];
#pragma unroll
                for (int k = 0; k < 64; ++k) acc += hid[R][k] * cw20[k * 32 + j];
            } else if (j < 48) {
                const int oc = j - 32; acc = cb21[oc];
#pragma unroll
                for (int k = 0; k < 32; ++k) acc += hid[R][64 + k] * cw21[k * 16 + oc];
            } else {
                const int oc = j - 48; acc = cb22[oc];
#pragma unroll
                for (int k = 0; k < 32; ++k) acc += hid[R][96 + k] * cw22[k * 16 + oc];
            }
            dex[R][j] = expf(sigf(acc));
        }
        __syncthreads();
        // ---------------- z = softmax(d) ----------------
        if (ct < 128) {
            const int r2 = ct >> 6, l = ct & 63;
            const int R = R0 + r2;
            float v = dex[R][l];
#pragma unroll
            for (int s = 32; s >= 1; s >>= 1) v += __shfl_xor(v, s);
            if (l == 0) zsum[R] = v;
        }
        __syncthreads();
        if (ct < 128) {
            const int r2 = ct >> 6, j = ct & 63;
            const int R = R0 + r2;
            zz[R][j] = dex[R][j] / zsum[R];
        }
        __syncthreads();
    }

    // ---------------- final MLP: relu([z|h]@fw1 + fb1) @ fw2 + fb2 ----------------
    if (ct < 128) {
        const int j = ct & 63, r2 = ct >> 6;
        const int R = R0 + r2;
        float acc = fb1[j];
#pragma unroll 16
        for (int k = 0; k < 64; ++k)  acc += zz[R][k] * fw1[k * 64 + j];
#pragma unroll 16
        for (int k = 0; k < 192; ++k) acc += hcat[R][k] * fw1[(64 + k) * 64 + j];
        hid[R][j] = fmaxf(acc, 0.f);
    }
    __syncthreads();
    if (ct < 128) {
        const int j = ct & 63, r2 = ct >> 6;
        const int R = R0 + r2;
        float v = hid[R][j] * fw2[j];
#pragma unroll
        for (int s = 32; s >= 1; s >>= 1) v += __shfl_xor(v, s);
        if (j == 0) out[row0 + R] = v + fb2[0];
    }
}

// ---------------------------------------------------------------------------
extern "C" void kernel_launch(void* const* d_in, const int* in_sizes, int n_in,
                              void* d_out, int out_size, void* d_ws, size_t ws_size,
                              hipStream_t stream) {
    const float* x0   = (const float*)d_in[0];
    const float* x1   = (const float*)d_in[1];
    const float* x2   = (const float*)d_in[2];
    const float* W0   = (const float*)d_in[3];
    const float* U0   = (const float*)d_in[4];
    const float* V0   = (const float*)d_in[5];
    const float* b0   = (const float*)d_in[6];
    const float* W1   = (const float*)d_in[7];
    const float* U1   = (const float*)d_in[8];
    const float* V1   = (const float*)d_in[9];
    const float* b1   = (const float*)d_in[10];
    const float* W2   = (const float*)d_in[11];
    const float* U2   = (const float*)d_in[12];
    const float* V2   = (const float*)d_in[13];
    const float* b2   = (const float*)d_in[14];
    const float* aw1  = (const float*)d_in[15];
    const float* ab1  = (const float*)d_in[16];
    const float* aw2  = (const float*)d_in[17];
    const float* ab2  = (const float*)d_in[18];
    const float* cw10 = (const float*)d_in[19];
    const float* cb10 = (const float*)d_in[20];
    const float* cw20 = (const float*)d_in[21];
    const float* cb20 = (const float*)d_in[22];
    const float* cw11 = (const float*)d_in[23];
    const float* cb11 = (const float*)d_in[24];
    const float* cw21 = (const float*)d_in[25];
    const float* cb21 = (const float*)d_in[26];
    const float* cw12 = (const float*)d_in[27];
    const float* cb12 = (const float*)d_in[28];
    const float* cw22 = (const float*)d_in[29];
    const float* cb22 = (const float*)d_in[30];
    const float* fw1  = (const float*)d_in[31];
    const float* fb1  = (const float*)d_in[32];
    const float* fw2  = (const float*)d_in[33];
    const float* fb2  = (const float*)d_in[34];
    float* out = (float*)d_out;

    const size_t M = (size_t)BB * TT;   // 65536
    float* G0 = (float*)d_ws;                 // [M, 512]
    float* G1 = G0 + M * 512;                 // [M, 128]
    float* G2 = G1 + M * 128;                 // [M, 128]

    // Precompute x@W + b for all (b,t)
    xw_gemm<<<dim3(512 / GT_N, M / GT_M), 256, 0, stream>>>(x0, W0, b0, G0, (int)M, 512, 300);
    xw_gemm<<<dim3(128 / GT_N, M / GT_M), 256, 0, stream>>>(x1, W1, b1, G1, (int)M, 128, 74);
    xw_gemm<<<dim3(128 / GT_N, M / GT_M), 256, 0, stream>>>(x2, W2, b2, G2, (int)M, 128, 35);

    // Persistent recurrence: 64 blocks x 512 threads, 4 rows/block
    marn_rec<<<64, 512, 0, stream>>>(G0, G1, G2, U0, V0, U1, V1, U2, V2,
                                     aw1, ab1, aw2, ab2,
                                     cw10, cb10, cw20, cb20,
                                     cw11, cb11, cw21, cb21,
                                     cw12, cb12, cw22, cb22,
                                     fw1, fb1, fw2, fb2, out);
}

// Round 2
// 10266.946 us; speedup vs baseline: 1.2016x; 1.2016x over previous
//
#include <hip/hip_runtime.h>
#include <hip/hip_bf16.h>
#include <math.h>

// Problem constants (from reference)
#define BB 256
#define TT 256
// H = [128,32,32], TH=192, ZDIM=64, ATT=4

__device__ __forceinline__ float sigf(float x) { return 1.f / (1.f + expf(-x)); }

// ---------------------------------------------------------------------------
// Kernel 1: G = X @ W + bias   (X: [M,K], W: [K,N], G: [M,N])
// ---------------------------------------------------------------------------
#define GT_M 128
#define GT_N 64
#define GT_K 16

__global__ __launch_bounds__(256)
void xw_gemm(const float* __restrict__ X, const float* __restrict__ W,
             const float* __restrict__ bias, float* __restrict__ G,
             int M, int N, int K) {
    __shared__ float As[GT_K][GT_M + 4];
    __shared__ float Bs[GT_K][GT_N];
    const int tid = threadIdx.x;
    const int bm = blockIdx.y * GT_M;
    const int bn = blockIdx.x * GT_N;
    const int tx = tid & 15;
    const int ty = tid >> 4;

    float acc[8][4];
#pragma unroll
    for (int i = 0; i < 8; ++i)
#pragma unroll
        for (int j = 0; j < 4; ++j) acc[i][j] = 0.f;

    for (int kt = 0; kt < K; kt += GT_K) {
#pragma unroll
        for (int i = 0; i < 8; ++i) {
            int idx = i * 256 + tid;
            int m = idx >> 4, k = idx & 15;
            int gk = kt + k;
            As[k][m] = (gk < K) ? X[(size_t)(bm + m) * K + gk] : 0.f;
        }
#pragma unroll
        for (int i = 0; i < 4; ++i) {
            int idx = i * 256 + tid;
            int k = idx >> 6, n = idx & 63;
            int gk = kt + k;
            Bs[k][n] = (gk < K) ? W[(size_t)gk * N + bn + n] : 0.f;
        }
        __syncthreads();
#pragma unroll
        for (int k = 0; k < GT_K; ++k) {
            float a[8], b[4];
            const float4 a0 = *(const float4*)&As[k][ty * 8];
            const float4 a1 = *(const float4*)&As[k][ty * 8 + 4];
            const float4 bv = *(const float4*)&Bs[k][tx * 4];
            a[0]=a0.x; a[1]=a0.y; a[2]=a0.z; a[3]=a0.w;
            a[4]=a1.x; a[5]=a1.y; a[6]=a1.z; a[7]=a1.w;
            b[0]=bv.x; b[1]=bv.y; b[2]=bv.z; b[3]=bv.w;
#pragma unroll
            for (int i = 0; i < 8; ++i)
#pragma unroll
                for (int j = 0; j < 4; ++j) acc[i][j] += a[i] * b[j];
        }
        __syncthreads();
    }
    const int n0 = bn + tx * 4;
#pragma unroll
    for (int i = 0; i < 8; ++i) {
        int m = bm + ty * 8 + i;
        float4 v;
        v.x = acc[i][0] + bias[n0 + 0];
        v.y = acc[i][1] + bias[n0 + 1];
        v.z = acc[i][2] + bias[n0 + 2];
        v.w = acc[i][3] + bias[n0 + 3];
        *(float4*)&G[(size_t)m * N + n0] = v;
    }
}

// ---------------------------------------------------------------------------
// Kernel 2: persistent recurrence. 128 blocks x 512 threads, 2 rows/block.
// All 512 threads cooperate on both rows: each weight float4 loaded ONCE per
// block, feeds 2 rows x 4 cols = 8 FMAs. Split-K partials reduced via LDS.
// ---------------------------------------------------------------------------
__global__ __launch_bounds__(512)
void marn_rec(const float* __restrict__ G0, const float* __restrict__ G1,
              const float* __restrict__ G2,
              const float* __restrict__ U0, const float* __restrict__ V0,
              const float* __restrict__ U1, const float* __restrict__ V1,
              const float* __restrict__ U2, const float* __restrict__ V2,
              const float* __restrict__ aw1, const float* __restrict__ ab1,
              const float* __restrict__ aw2, const float* __restrict__ ab2,
              const float* __restrict__ cw10, const float* __restrict__ cb10,
              const float* __restrict__ cw20, const float* __restrict__ cb20,
              const float* __restrict__ cw11, const float* __restrict__ cb11,
              const float* __restrict__ cw21, const float* __restrict__ cb21,
              const float* __restrict__ cw12, const float* __restrict__ cb12,
              const float* __restrict__ cw22, const float* __restrict__ cb22,
              const float* __restrict__ fw1, const float* __restrict__ fb1,
              const float* __restrict__ fw2, const float* __restrict__ fb2,
              float* __restrict__ out) {
    // state (2 rows)
    __shared__ float hcat[2][192];   // [h0(128)|h1(32)|h2(32)]
    __shared__ float cst[2][192];
    __shared__ float zz[2][64];
    __shared__ float a1s[2][256];
    __shared__ float attE[2][768];
    __shared__ float aout[2][768];
    __shared__ float hid[2][128];
    __shared__ float red[2][4];
    // split-K partials
    __shared__ float partA[3][2][512];     // stage A cell0
    __shared__ float partB[2][2][256];     // stage A cell1|cell2
    __shared__ float part1[8][2][256];     // att1
    __shared__ float part2[4][2][768];     // att2
    __shared__ float p1a[16][2][64];       // comp1 cell0
    __shared__ float p1b[2][8][2][32];     // comp1 cell1/2

    const int tid = threadIdx.x;
    const int row0 = blockIdx.x * 2;

    for (int i = tid; i < 2 * 192; i += 512) { (&hcat[0][0])[i] = 0.f; (&cst[0][0])[i] = 0.f; }
    for (int i = tid; i < 2 * 64; i += 512) (&zz[0][0])[i] = 0.f;
    __syncthreads();

    for (int t = 0; t < TT; ++t) {
        // ============ stage A compute: partials of h@U + z@V ============
        if (tid < 384) {
            // cell0: 128 col-groups x 3 K-chunks of 64
            const int g  = tid & 127, kc = tid >> 7;
            const int cb = g * 4;
            float4 acc0 = {0,0,0,0}, acc1 = {0,0,0,0};
            if (kc < 2) {
                const float* wb = U0 + (size_t)(64 * kc) * 512 + cb;
#pragma unroll 8
                for (int k = 0; k < 64; ++k) {
                    const float4 w = *(const float4*)(wb + (size_t)k * 512);
                    const float a0 = hcat[0][64 * kc + k], a1 = hcat[1][64 * kc + k];
                    acc0.x += w.x * a0; acc0.y += w.y * a0; acc0.z += w.z * a0; acc0.w += w.w * a0;
                    acc1.x += w.x * a1; acc1.y += w.y * a1; acc1.z += w.z * a1; acc1.w += w.w * a1;
                }
            } else {
                const float* wb = V0 + cb;
#pragma unroll 8
                for (int k = 0; k < 64; ++k) {
                    const float4 w = *(const float4*)(wb + (size_t)k * 512);
                    const float a0 = zz[0][k], a1 = zz[1][k];
                    acc0.x += w.x * a0; acc0.y += w.y * a0; acc0.z += w.z * a0; acc0.w += w.w * a0;
                    acc1.x += w.x * a1; acc1.y += w.y * a1; acc1.z += w.z * a1; acc1.w += w.w * a1;
                }
            }
            *(float4*)&partA[kc][0][cb] = acc0;
            *(float4*)&partA[kc][1][cb] = acc1;
        } else {
            // cell1/cell2: 64 col-groups x 2 K-chunks of 48  (K = 32 U + 64 V)
            const int u  = tid - 384;
            const int kc = u >> 6;
            const int g2 = u & 63;
            const int cell = g2 >> 5;            // 0 -> cell1, 1 -> cell2
            const int cb = (g2 & 31) * 4;
            const float* Ux = cell ? U2 : U1;
            const float* Vx = cell ? V2 : V1;
            const int hoff = 128 + 32 * cell;
            float4 acc0 = {0,0,0,0}, acc1 = {0,0,0,0};
            if (kc == 0) {
#pragma unroll 8
                for (int k = 0; k < 32; ++k) {
                    const float4 w = *(const float4*)(Ux + (size_t)k * 128 + cb);
                    const float a0 = hcat[0][hoff + k], a1 = hcat[1][hoff + k];
                    acc0.x += w.x * a0; acc0.y += w.y * a0; acc0.z += w.z * a0; acc0.w += w.w * a0;
                    acc1.x += w.x * a1; acc1.y += w.y * a1; acc1.z += w.z * a1; acc1.w += w.w * a1;
                }
#pragma unroll 8
                for (int k = 0; k < 16; ++k) {
                    const float4 w = *(const float4*)(Vx + (size_t)k * 128 + cb);
                    const float a0 = zz[0][k], a1 = zz[1][k];
                    acc0.x += w.x * a0; acc0.y += w.y * a0; acc0.z += w.z * a0; acc0.w += w.w * a0;
                    acc1.x += w.x * a1; acc1.y += w.y * a1; acc1.z += w.z * a1; acc1.w += w.w * a1;
                }
            } else {
#pragma unroll 8
                for (int k = 16; k < 64; ++k) {
                    const float4 w = *(const float4*)(Vx + (size_t)k * 128 + cb);
                    const float a0 = zz[0][k], a1 = zz[1][k];
                    acc0.x += w.x * a0; acc0.y += w.y * a0; acc0.z += w.z * a0; acc0.w += w.w * a0;
                    acc1.x += w.x * a1; acc1.y += w.y * a1; acc1.z += w.z * a1; acc1.w += w.w * a1;
                }
            }
            const int colB = cell * 128 + cb;
            *(float4*)&partB[kc][0][colB] = acc0;
            *(float4*)&partB[kc][1][colB] = acc1;
        }
        __syncthreads();
        // ============ stage A reduce + gates -> c, h ============
        if (tid < 256) {
            const int r = tid >> 7, u = tid & 127;
            const float* gp = G0 + ((size_t)(row0 + r) * TT + t) * 512;
            float s[4];
#pragma unroll
            for (int q = 0; q < 4; ++q) {
                const int c4 = q * 128 + u;
                s[q] = gp[c4] + partA[0][r][c4] + partA[1][r][c4] + partA[2][r][c4];
            }
            const float f  = sigf(s[0]);
            const float ig = sigf(s[1]);
            const float o  = sigf(s[2]);
            const float ch = tanhf(s[3]);
            const float c = f * cst[r][u] + ig * ch;
            cst[r][u] = c;
            hcat[r][u] = tanhf(c) * o;
        } else if (tid < 384) {
            const int v = tid - 256;
            const int r = v >> 6, u6 = v & 63;
            const int cell = u6 >> 5, uu = u6 & 31;
            const float* gp = (cell ? G2 : G1) + ((size_t)(row0 + r) * TT + t) * 128;
            float s[4];
#pragma unroll
            for (int q = 0; q < 4; ++q) {
                const int gc = q * 32 + uu;
                s[q] = gp[gc] + partB[0][r][cell * 128 + gc] + partB[1][r][cell * 128 + gc];
            }
            const float f  = sigf(s[0]);
            const float ig = sigf(s[1]);
            const float o  = sigf(s[2]);
            const float ch = tanhf(s[3]);
            const int si = 128 + 32 * cell + uu;
            const float c = f * cst[r][si] + ig * ch;
            cst[r][si] = c;
            hcat[r][si] = tanhf(c) * o;
        }
        __syncthreads();
        // ============ att1 compute: 64 groups x 8 K-chunks of 24 ============
        {
            const int g = tid & 63, kc = tid >> 6;
            const int cb = g * 4;
            const float* wb = aw1 + (size_t)(24 * kc) * 256 + cb;
            float4 acc0 = {0,0,0,0}, acc1 = {0,0,0,0};
#pragma unroll 8
            for (int k = 0; k < 24; ++k) {
                const float4 w = *(const float4*)(wb + (size_t)k * 256);
                const float a0 = hcat[0][24 * kc + k], a1 = hcat[1][24 * kc + k];
                acc0.x += w.x * a0; acc0.y += w.y * a0; acc0.z += w.z * a0; acc0.w += w.w * a0;
                acc1.x += w.x * a1; acc1.y += w.y * a1; acc1.z += w.z * a1; acc1.w += w.w * a1;
            }
            *(float4*)&part1[kc][0][cb] = acc0;
            *(float4*)&part1[kc][1][cb] = acc1;
        }
        __syncthreads();
        // ============ att1 reduce + relu ============
        {
            const int r = tid >> 8, col = tid & 255;
            float s = ab1[col];
#pragma unroll
            for (int kc = 0; kc < 8; ++kc) s += part1[kc][r][col];
            a1s[r][col] = fmaxf(s, 0.f);
        }
        __syncthreads();
        // ============ att2 compute: 192 groups x 4 K-chunks of 64 ============
        for (int tt = tid; tt < 768; tt += 512) {
            const int kc = tt / 192;
            const int g  = tt - kc * 192;
            const int cb = g * 4;
            const float* wb = aw2 + (size_t)(64 * kc) * 768 + cb;
            float4 acc0 = {0,0,0,0}, acc1 = {0,0,0,0};
#pragma unroll 8
            for (int k = 0; k < 64; ++k) {
                const float4 w = *(const float4*)(wb + (size_t)k * 768);
                const float a0 = a1s[0][64 * kc + k], a1 = a1s[1][64 * kc + k];
                acc0.x += w.x * a0; acc0.y += w.y * a0; acc0.z += w.z * a0; acc0.w += w.w * a0;
                acc1.x += w.x * a1; acc1.y += w.y * a1; acc1.z += w.z * a1; acc1.w += w.w * a1;
            }
            *(float4*)&part2[kc][0][cb] = acc0;
            *(float4*)&part2[kc][1][cb] = acc1;
        }
        __syncthreads();
        // ============ att2 reduce + sigmoid + exp ============
#pragma unroll
        for (int i = 0; i < 3; ++i) {
            const int idx = i * 512 + tid;
            const int r = idx >= 768;
            const int col = idx - r * 768;
            float s = ab2[col];
#pragma unroll
            for (int kc = 0; kc < 4; ++kc) s += part2[kc][r][col];
            attE[r][col] = expf(sigf(s));
        }
        __syncthreads();
        // ============ softmax denominators (8 waves -> 8 (r,head) sums) ====
        {
            const int w = tid >> 6, lane = tid & 63;
            const int r = w >> 2, a = w & 3;
            float v = attE[r][a * 192 + lane] + attE[r][a * 192 + 64 + lane]
                    + attE[r][a * 192 + 128 + lane];
#pragma unroll
            for (int s = 32; s >= 1; s >>= 1) v += __shfl_xor(v, s);
            if (lane == 0) red[r][a] = v;
        }
        __syncthreads();
        // ============ att_out = softmax * tiled(h) ============
#pragma unroll
        for (int i = 0; i < 3; ++i) {
            const int idx = i * 512 + tid;
            const int r = idx >= 768;
            const int col = idx - r * 768;
            const int a = col / 192;
            const float atv = attE[r][col] / red[r][a];
            const float ot = (col < 512) ? hcat[r][col & 127]
                           : (col < 640) ? hcat[r][128 + ((col - 512) & 31)]
                                         : hcat[r][160 + ((col - 640) & 31)];
            aout[r][col] = atv * ot;
        }
        __syncthreads();
        // ============ comp1 compute ============
        if (tid < 256) {
            // cell0: 16 groups x 16 K-chunks of 32 (K=512)
            const int g = tid & 15, kc = tid >> 4;
            const int cb = g * 4;
            const float* wb = cw10 + (size_t)(32 * kc) * 64 + cb;
            float4 acc0 = {0,0,0,0}, acc1 = {0,0,0,0};
#pragma unroll 8
            for (int k = 0; k < 32; ++k) {
                const float4 w = *(const float4*)(wb + (size_t)k * 64);
                const float a0 = aout[0][32 * kc + k], a1 = aout[1][32 * kc + k];
                acc0.x += w.x * a0; acc0.y += w.y * a0; acc0.z += w.z * a0; acc0.w += w.w * a0;
                acc1.x += w.x * a1; acc1.y += w.y * a1; acc1.z += w.z * a1; acc1.w += w.w * a1;
            }
            *(float4*)&p1a[kc][0][cb] = acc0;
            *(float4*)&p1a[kc][1][cb] = acc1;
        } else if (tid < 384) {
            // cell1/2: 8 groups x 8 K-chunks of 16 (K=128)
            const int u = tid - 256;
            const int cell = u >> 6;
            const int rem = u & 63;
            const int g = rem & 7, kc = rem >> 3;
            const int cb = g * 4;
            const float* wb = (cell ? cw12 : cw11) + (size_t)(16 * kc) * 32 + cb;
            const int aoff = 512 + 128 * cell + 16 * kc;
            float4 acc0 = {0,0,0,0}, acc1 = {0,0,0,0};
#pragma unroll 8
            for (int k = 0; k < 16; ++k) {
                const float4 w = *(const float4*)(wb + (size_t)k * 32);
                const float a0 = aout[0][aoff + k], a1 = aout[1][aoff + k];
                acc0.x += w.x * a0; acc0.y += w.y * a0; acc0.z += w.z * a0; acc0.w += w.w * a0;
                acc1.x += w.x * a1; acc1.y += w.y * a1; acc1.z += w.z * a1; acc1.w += w.w * a1;
            }
            *(float4*)&p1b[cell][kc][0][cb] = acc0;
            *(float4*)&p1b[cell][kc][1][cb] = acc1;
        }
        __syncthreads();
        // ============ comp1 reduce + relu ============
        if (tid < 256) {
            const int r = tid >> 7, col = tid & 127;
            float s;
            if (col < 64) {
                s = cb10[col];
#pragma unroll
                for (int kc = 0; kc < 16; ++kc) s += p1a[kc][r][col];
            } else {
                const int cc = col - 64;
                const int cell = cc >> 5, j = cc & 31;
                s = (cell ? cb12 : cb11)[j];
#pragma unroll
                for (int kc = 0; kc < 8; ++kc) s += p1b[cell][kc][r][j];
            }
            hid[r][col] = fmaxf(s, 0.f);
        }
        __syncthreads();
        // ============ comp2 + z softmax (wave r handles row r) ============
        if (tid < 128) {
            const int r = tid >> 6, j = tid & 63;
            float acc;
            if (j < 32) {
                acc = cb20[j];
#pragma unroll
                for (int k = 0; k < 64; ++k) acc += hid[r][k] * cw20[k * 32 + j];
            } else if (j < 48) {
                const int o = j - 32; acc = cb21[o];
#pragma unroll
                for (int k = 0; k < 32; ++k) acc += hid[r][64 + k] * cw21[k * 16 + o];
            } else {
                const int o = j - 48; acc = cb22[o];
#pragma unroll
                for (int k = 0; k < 32; ++k) acc += hid[r][96 + k] * cw22[k * 16 + o];
            }
            const float e = expf(sigf(acc));
            float v = e;
#pragma unroll
            for (int s = 32; s >= 1; s >>= 1) v += __shfl_xor(v, s);
            zz[r][j] = e / v;
        }
        __syncthreads();
    }

    // ============ final MLP ============
    if (tid < 128) {
        const int r = tid >> 6, j = tid & 63;
        float acc = fb1[j];
#pragma unroll 8
        for (int k = 0; k < 64; ++k)  acc += zz[r][k] * fw1[k * 64 + j];
#pragma unroll 8
        for (int k = 0; k < 192; ++k) acc += hcat[r][k] * fw1[(64 + k) * 64 + j];
        hid[r][j] = fmaxf(acc, 0.f);
    }
    __syncthreads();
    if (tid < 128) {
        const int r = tid >> 6, j = tid & 63;
        float v = hid[r][j] * fw2[j];
#pragma unroll
        for (int s = 32; s >= 1; s >>= 1) v += __shfl_xor(v, s);
        if (j == 0) out[row0 + r] = v + fb2[0];
    }
}

// ---------------------------------------------------------------------------
extern "C" void kernel_launch(void* const* d_in, const int* in_sizes, int n_in,
                              void* d_out, int out_size, void* d_ws, size_t ws_size,
                              hipStream_t stream) {
    const float* x0   = (const float*)d_in[0];
    const float* x1   = (const float*)d_in[1];
    const float* x2   = (const float*)d_in[2];
    const float* W0   = (const float*)d_in[3];
    const float* U0   = (const float*)d_in[4];
    const float* V0   = (const float*)d_in[5];
    const float* b0   = (const float*)d_in[6];
    const float* W1   = (const float*)d_in[7];
    const float* U1   = (const float*)d_in[8];
    const float* V1   = (const float*)d_in[9];
    const float* b1   = (const float*)d_in[10];
    const float* W2   = (const float*)d_in[11];
    const float* U2   = (const float*)d_in[12];
    const float* V2   = (const float*)d_in[13];
    const float* b2   = (const float*)d_in[14];
    const float* aw1  = (const float*)d_in[15];
    const float* ab1  = (const float*)d_in[16];
    const float* aw2  = (const float*)d_in[17];
    const float* ab2  = (const float*)d_in[18];
    const float* cw10 = (const float*)d_in[19];
    const float* cb10 = (const float*)d_in[20];
    const float* cw20 = (const float*)d_in[21];
    const float* cb20 = (const float*)d_in[22];
    const float* cw11 = (const float*)d_in[23];
    const float* cb11 = (const float*)d_in[24];
    const float* cw21 = (const float*)d_in[25];
    const float* cb21 = (const float*)d_in[26];
    const float* cw12 = (const float*)d_in[27];
    const float* cb12 = (const float*)d_in[28];
    const float* cw22 = (const float*)d_in[29];
    const float* cb22 = (const float*)d_in[30];
    const float* fw1  = (const float*)d_in[31];
    const float* fb1  = (const float*)d_in[32];
    const float* fw2  = (const float*)d_in[33];
    const float* fb2  = (const float*)d_in[34];
    float* out = (float*)d_out;

    const size_t M = (size_t)BB * TT;   // 65536
    float* G0 = (float*)d_ws;                 // [M, 512]
    float* G1 = G0 + M * 512;                 // [M, 128]
    float* G2 = G1 + M * 128;                 // [M, 128]

    xw_gemm<<<dim3(512 / GT_N, M / GT_M), 256, 0, stream>>>(x0, W0, b0, G0, (int)M, 512, 300);
    xw_gemm<<<dim3(128 / GT_N, M / GT_M), 256, 0, stream>>>(x1, W1, b1, G1, (int)M, 128, 74);
    xw_gemm<<<dim3(128 / GT_N, M / GT_M), 256, 0, stream>>>(x2, W2, b2, G2, (int)M, 128, 35);

    // 128 blocks x 512 threads, 2 rows/block
    marn_rec<<<128, 512, 0, stream>>>(G0, G1, G2, U0, V0, U1, V1, U2, V2,
                                      aw1, ab1, aw2, ab2,
                                      cw10, cb10, cw20, cb20,
                                      cw11, cb11, cw21, cb21,
                                      cw12, cb12, cw22, cb22,
                                      fw1, fb1, fw2, fb2, out);
}

// Round 3
// 8789.311 us; speedup vs baseline: 1.4036x; 1.1681x over previous
//
#include <hip/hip_runtime.h>
#include <hip/hip_bf16.h>
#include <hip/hip_fp16.h>
#include <math.h>

// Problem constants (from reference)
#define BB 256
#define TT 256
// H = [128,32,32], TH=192, ZDIM=64, ATT=4

__device__ __forceinline__ float sigf(float x) { return 1.f / (1.f + expf(-x)); }

// ---------------------------------------------------------------------------
// fp32 -> fp16 conversion
// ---------------------------------------------------------------------------
__global__ void f2h(const float* __restrict__ s, __half* __restrict__ d, int n) {
    int i = blockIdx.x * 256 + threadIdx.x;
    if (i < n) d[i] = __float2half(s[i]);
}

// ---------------------------------------------------------------------------
// Kernel 1: G = X @ W + bias   (X: [M,K], W: [K,N], G: [M,N]), OT = fp32|fp16
// ---------------------------------------------------------------------------
#define GT_M 128
#define GT_N 64
#define GT_K 16

__device__ __forceinline__ void stvec4(float* p, float4 v) { *(float4*)p = v; }
__device__ __forceinline__ void stvec4(__half* p, float4 v) {
    __half2 h01 = __floats2half2_rn(v.x, v.y);
    __half2 h23 = __floats2half2_rn(v.z, v.w);
    *(__half2*)p = h01;
    *(__half2*)(p + 2) = h23;
}

template <typename OT>
__global__ __launch_bounds__(256)
void xw_gemm(const float* __restrict__ X, const float* __restrict__ W,
             const float* __restrict__ bias, OT* __restrict__ G,
             int M, int N, int K) {
    __shared__ float As[GT_K][GT_M + 4];
    __shared__ float Bs[GT_K][GT_N];
    const int tid = threadIdx.x;
    const int bm = blockIdx.y * GT_M;
    const int bn = blockIdx.x * GT_N;
    const int tx = tid & 15;
    const int ty = tid >> 4;

    float acc[8][4];
#pragma unroll
    for (int i = 0; i < 8; ++i)
#pragma unroll
        for (int j = 0; j < 4; ++j) acc[i][j] = 0.f;

    for (int kt = 0; kt < K; kt += GT_K) {
#pragma unroll
        for (int i = 0; i < 8; ++i) {
            int idx = i * 256 + tid;
            int m = idx >> 4, k = idx & 15;
            int gk = kt + k;
            As[k][m] = (gk < K) ? X[(size_t)(bm + m) * K + gk] : 0.f;
        }
#pragma unroll
        for (int i = 0; i < 4; ++i) {
            int idx = i * 256 + tid;
            int k = idx >> 6, n = idx & 63;
            int gk = kt + k;
            Bs[k][n] = (gk < K) ? W[(size_t)gk * N + bn + n] : 0.f;
        }
        __syncthreads();
#pragma unroll
        for (int k = 0; k < GT_K; ++k) {
            float a[8], b[4];
            const float4 a0 = *(const float4*)&As[k][ty * 8];
            const float4 a1 = *(const float4*)&As[k][ty * 8 + 4];
            const float4 bv = *(const float4*)&Bs[k][tx * 4];
            a[0]=a0.x; a[1]=a0.y; a[2]=a0.z; a[3]=a0.w;
            a[4]=a1.x; a[5]=a1.y; a[6]=a1.z; a[7]=a1.w;
            b[0]=bv.x; b[1]=bv.y; b[2]=bv.z; b[3]=bv.w;
#pragma unroll
            for (int i = 0; i < 8; ++i)
#pragma unroll
                for (int j = 0; j < 4; ++j) acc[i][j] += a[i] * b[j];
        }
        __syncthreads();
    }
    const int n0 = bn + tx * 4;
#pragma unroll
    for (int i = 0; i < 8; ++i) {
        int m = bm + ty * 8 + i;
        float4 v;
        v.x = acc[i][0] + bias[n0 + 0];
        v.y = acc[i][1] + bias[n0 + 1];
        v.z = acc[i][2] + bias[n0 + 2];
        v.w = acc[i][3] + bias[n0 + 3];
        stvec4(&G[(size_t)m * N + n0], v);
    }
}

// ---------------------------------------------------------------------------
// Kernel 2: persistent recurrence. 128 blocks x 512 threads, 2 rows/block.
// fp16 weights, 8-col groups (one 16B load = 8 weights -> 16 FMAs).
// Split-K partials in aliased LDS scratch.
// ---------------------------------------------------------------------------
__global__ __launch_bounds__(512)
void marn_rec(const float* __restrict__ G0, const __half* __restrict__ G1h,
              const __half* __restrict__ G2h,
              const __half* __restrict__ hU0, const __half* __restrict__ hV0,
              const __half* __restrict__ hU1, const __half* __restrict__ hV1,
              const __half* __restrict__ hU2, const __half* __restrict__ hV2,
              const __half* __restrict__ haw1, const float* __restrict__ ab1,
              const __half* __restrict__ haw2, const float* __restrict__ ab2,
              const __half* __restrict__ hcw10, const float* __restrict__ cb10,
              const float* __restrict__ cw20, const float* __restrict__ cb20,
              const __half* __restrict__ hcw11, const float* __restrict__ cb11,
              const float* __restrict__ cw21, const float* __restrict__ cb21,
              const __half* __restrict__ hcw12, const float* __restrict__ cb12,
              const float* __restrict__ cw22, const float* __restrict__ cb22,
              const float* __restrict__ fw1, const float* __restrict__ fb1,
              const float* __restrict__ fw2, const float* __restrict__ fb2,
              float* __restrict__ out) {
    // state: hz = [h0(128)|h1(32)|h2(32)|z(64)]
    __shared__ float hz[2][256];
    __shared__ float cst[2][192];
    __shared__ float a1s[2][256];
    __shared__ float attE[2][768];
    __shared__ float aout[2][768];
    __shared__ float hid[2][128];
    __shared__ float red[2][4];
    __shared__ float scratch[7680];   // 30KB, aliased across stages

    const int tid = threadIdx.x;
    const int row0 = blockIdx.x * 2;

    for (int i = tid; i < 2 * 256; i += 512) (&hz[0][0])[i] = 0.f;
    for (int i = tid; i < 2 * 192; i += 512) (&cst[0][0])[i] = 0.f;
    __syncthreads();

    // ---- per-thread precompute for stage A (480 active threads) ----
    const __half* WBa = nullptr; int HOa = 0, STRa = 0, SOa = 0, SRa = 0;
    int a12cell = 0;
    if (tid < 384) {
        const int g = tid & 63, kc = tid >> 6;         // kc 0..5
        const int cb = g * 8;
        if (kc < 4) { WBa = hU0 + (size_t)(32 * kc) * 512 + cb; HOa = 32 * kc; }
        else        { WBa = hV0 + (size_t)(32 * (kc - 4)) * 512 + cb; HOa = 192 + 32 * (kc - 4); }
        STRa = 512;
        SOa = kc * 1024 + cb;      // + r*512
        SRa = 512;
    } else if (tid < 480) {
        const int u = tid - 384;                       // 0..95
        const int kc = u >> 5;                         // 0..2
        const int g2 = u & 31;
        const int cell = g2 >> 4;                      // 0|1
        const int cb = (g2 & 15) * 8;
        const __half* Uc = cell ? hU2 : hU1;
        const __half* Vc = cell ? hV2 : hV1;
        if (kc == 0) { WBa = Uc + cb; HOa = 128 + 32 * cell; }
        else         { WBa = Vc + (size_t)(32 * (kc - 1)) * 128 + cb; HOa = 192 + 32 * (kc - 1); }
        STRa = 128;
        SOa = 6144 + kc * 512 + cell * 128 + cb;   // + r*256
        SRa = 256;
        a12cell = cell;
    }
    // att1 precompute (256 active)
    const __half* WB1 = nullptr; int HO1 = 0, SO1 = 0;
    if (tid < 256) {
        const int g = tid & 31, kc = tid >> 5;         // kc 0..7
        const int cb = g * 8;
        WB1 = haw1 + (size_t)(24 * kc) * 256 + cb;
        HO1 = 24 * kc;
        SO1 = kc * 512 + cb;       // + r*256
    }
    // att2 precompute (384 active)
    const int kc2 = tid / 96;
    const int g2a = tid - kc2 * 96;
    const __half* WB2 = haw2 + (size_t)(64 * kc2) * 768 + g2a * 8;
    const int HO2 = 64 * kc2;
    const int SO2 = kc2 * 1536 + g2a * 8;              // + r*768
    // comp1 precompute (320 active)
    const __half* WBc = nullptr; int HOc = 0, SOc = 0, KNc = 0;
    if (tid < 256) {
        const int g = tid & 7, kc = tid >> 3;          // kc 0..31
        WBc = hcw10 + (size_t)(16 * kc) * 64 + g * 8;
        HOc = 16 * kc;
        SOc = kc * 128 + g * 8;    // + r*64
        KNc = 64;
    } else if (tid < 320) {
        const int u = tid - 256;                       // 0..63
        const int cell = u >> 5;
        const int rem = u & 31;
        const int g = rem & 3, kc = rem >> 2;          // kc 0..7
        WBc = (cell ? hcw12 : hcw11) + (size_t)(16 * kc) * 32 + g * 8;
        HOc = 512 + 128 * cell + 16 * kc;
        SOc = 4096 + cell * 512 + kc * 64 + g * 8;     // + r*32
        KNc = 32;
    }

    for (int t = 0; t < TT; ++t) {
        // ============ stage A compute: partials of [h|z]@[U;V] ============
        if (tid < 480) {
            float acc0[8], acc1[8];
#pragma unroll
            for (int j = 0; j < 8; ++j) { acc0[j] = 0.f; acc1[j] = 0.f; }
#pragma unroll 8
            for (int k = 0; k < 32; ++k) {
                const float4 wv = *(const float4*)(WBa + (size_t)k * STRa);
                const __half* hw = (const __half*)&wv;
                const float a0 = hz[0][HOa + k];
                const float a1 = hz[1][HOa + k];
#pragma unroll
                for (int j = 0; j < 8; ++j) {
                    const float w = __half2float(hw[j]);
                    acc0[j] += w * a0;
                    acc1[j] += w * a1;
                }
            }
            float* s0 = &scratch[SOa];
            float* s1 = &scratch[SOa + SRa];
            *(float4*)s0       = make_float4(acc0[0], acc0[1], acc0[2], acc0[3]);
            *(float4*)(s0 + 4) = make_float4(acc0[4], acc0[5], acc0[6], acc0[7]);
            *(float4*)s1       = make_float4(acc1[0], acc1[1], acc1[2], acc1[3]);
            *(float4*)(s1 + 4) = make_float4(acc1[4], acc1[5], acc1[6], acc1[7]);
        }
        __syncthreads();
        // ============ stage A reduce + gates -> c, h ============
        if (tid < 256) {
            const int r = tid >> 7, u = tid & 127;
            const float* gp = G0 + ((size_t)(row0 + r) * TT + t) * 512;
            float s[4];
#pragma unroll
            for (int q = 0; q < 4; ++q) {
                const int c4 = q * 128 + u;
                float v = gp[c4];
#pragma unroll
                for (int kc = 0; kc < 6; ++kc) v += scratch[kc * 1024 + r * 512 + c4];
                s[q] = v;
            }
            const float f  = sigf(s[0]);
            const float ig = sigf(s[1]);
            const float o  = sigf(s[2]);
            const float ch = tanhf(s[3]);
            const float c = f * cst[r][u] + ig * ch;
            cst[r][u] = c;
            hz[r][u] = tanhf(c) * o;
        } else if (tid < 384) {
            const int v6 = tid - 256;
            const int r = v6 >> 6, u6 = v6 & 63;
            const int cell = u6 >> 5, uu = u6 & 31;
            const __half* gp = (cell ? G2h : G1h) + ((size_t)(row0 + r) * TT + t) * 128;
            float s[4];
#pragma unroll
            for (int q = 0; q < 4; ++q) {
                const int gc = q * 32 + uu;
                float v = __half2float(gp[gc]);
#pragma unroll
                for (int kc = 0; kc < 3; ++kc)
                    v += scratch[6144 + kc * 512 + r * 256 + cell * 128 + gc];
                s[q] = v;
            }
            const float f  = sigf(s[0]);
            const float ig = sigf(s[1]);
            const float o  = sigf(s[2]);
            const float ch = tanhf(s[3]);
            const int si = 128 + 32 * cell + uu;
            const float c = f * cst[r][si] + ig * ch;
            cst[r][si] = c;
            hz[r][si] = tanhf(c) * o;
        }
        __syncthreads();
        // ============ att1 compute: 32 groups x 8 K-chunks of 24 ============
        if (tid < 256) {
            float acc0[8], acc1[8];
#pragma unroll
            for (int j = 0; j < 8; ++j) { acc0[j] = 0.f; acc1[j] = 0.f; }
#pragma unroll 8
            for (int k = 0; k < 24; ++k) {
                const float4 wv = *(const float4*)(WB1 + (size_t)k * 256);
                const __half* hw = (const __half*)&wv;
                const float a0 = hz[0][HO1 + k];
                const float a1 = hz[1][HO1 + k];
#pragma unroll
                for (int j = 0; j < 8; ++j) {
                    const float w = __half2float(hw[j]);
                    acc0[j] += w * a0;
                    acc1[j] += w * a1;
                }
            }
            float* s0 = &scratch[SO1];
            float* s1 = &scratch[SO1 + 256];
            *(float4*)s0       = make_float4(acc0[0], acc0[1], acc0[2], acc0[3]);
            *(float4*)(s0 + 4) = make_float4(acc0[4], acc0[5], acc0[6], acc0[7]);
            *(float4*)s1       = make_float4(acc1[0], acc1[1], acc1[2], acc1[3]);
            *(float4*)(s1 + 4) = make_float4(acc1[4], acc1[5], acc1[6], acc1[7]);
        }
        __syncthreads();
        // ============ att1 reduce + relu ============
        {
            const int r = tid >> 8, col = tid & 255;
            float s = ab1[col];
#pragma unroll
            for (int kc = 0; kc < 8; ++kc) s += scratch[kc * 512 + r * 256 + col];
            a1s[r][col] = fmaxf(s, 0.f);
        }
        __syncthreads();
        // ============ att2 compute: 96 groups x 4 K-chunks of 64 ============
        if (tid < 384) {
            float acc0[8], acc1[8];
#pragma unroll
            for (int j = 0; j < 8; ++j) { acc0[j] = 0.f; acc1[j] = 0.f; }
#pragma unroll 8
            for (int k = 0; k < 64; ++k) {
                const float4 wv = *(const float4*)(WB2 + (size_t)k * 768);
                const __half* hw = (const __half*)&wv;
                const float a0 = a1s[0][HO2 + k];
                const float a1 = a1s[1][HO2 + k];
#pragma unroll
                for (int j = 0; j < 8; ++j) {
                    const float w = __half2float(hw[j]);
                    acc0[j] += w * a0;
                    acc1[j] += w * a1;
                }
            }
            float* s0 = &scratch[SO2];
            float* s1 = &scratch[SO2 + 768];
            *(float4*)s0       = make_float4(acc0[0], acc0[1], acc0[2], acc0[3]);
            *(float4*)(s0 + 4) = make_float4(acc0[4], acc0[5], acc0[6], acc0[7]);
            *(float4*)s1       = make_float4(acc1[0], acc1[1], acc1[2], acc1[3]);
            *(float4*)(s1 + 4) = make_float4(acc1[4], acc1[5], acc1[6], acc1[7]);
        }
        __syncthreads();
        // ============ att2 reduce + sigmoid + exp ============
#pragma unroll
        for (int i = 0; i < 3; ++i) {
            const int idx = i * 512 + tid;
            const int r = idx >= 768;
            const int col = idx - r * 768;
            float s = ab2[col];
#pragma unroll
            for (int kc = 0; kc < 4; ++kc) s += scratch[kc * 1536 + r * 768 + col];
            attE[r][col] = expf(sigf(s));
        }
        __syncthreads();
        // ============ softmax denominators ============
        {
            const int w = tid >> 6, lane = tid & 63;
            const int r = w >> 2, a = w & 3;
            float v = attE[r][a * 192 + lane] + attE[r][a * 192 + 64 + lane]
                    + attE[r][a * 192 + 128 + lane];
#pragma unroll
            for (int s = 32; s >= 1; s >>= 1) v += __shfl_xor(v, s);
            if (lane == 0) red[r][a] = v;
        }
        __syncthreads();
        // ============ att_out = softmax * tiled(h) ============
#pragma unroll
        for (int i = 0; i < 3; ++i) {
            const int idx = i * 512 + tid;
            const int r = idx >= 768;
            const int col = idx - r * 768;
            const int a = col / 192;
            const float atv = attE[r][col] / red[r][a];
            const float ot = (col < 512) ? hz[r][col & 127]
                           : (col < 640) ? hz[r][128 + ((col - 512) & 31)]
                                         : hz[r][160 + ((col - 640) & 31)];
            aout[r][col] = atv * ot;
        }
        __syncthreads();
        // ============ comp1 compute ============
        if (tid < 320) {
            float acc0[8], acc1[8];
#pragma unroll
            for (int j = 0; j < 8; ++j) { acc0[j] = 0.f; acc1[j] = 0.f; }
#pragma unroll 8
            for (int k = 0; k < 16; ++k) {
                const float4 wv = *(const float4*)(WBc + (size_t)k * KNc);
                const __half* hw = (const __half*)&wv;
                const float a0 = aout[0][HOc + k];
                const float a1 = aout[1][HOc + k];
#pragma unroll
                for (int j = 0; j < 8; ++j) {
                    const float w = __half2float(hw[j]);
                    acc0[j] += w * a0;
                    acc1[j] += w * a1;
                }
            }
            const int sr = (tid < 256) ? 64 : 32;
            float* s0 = &scratch[SOc];
            float* s1 = &scratch[SOc + sr];
            *(float4*)s0       = make_float4(acc0[0], acc0[1], acc0[2], acc0[3]);
            *(float4*)(s0 + 4) = make_float4(acc0[4], acc0[5], acc0[6], acc0[7]);
            *(float4*)s1       = make_float4(acc1[0], acc1[1], acc1[2], acc1[3]);
            *(float4*)(s1 + 4) = make_float4(acc1[4], acc1[5], acc1[6], acc1[7]);
        }
        __syncthreads();
        // ============ comp1 reduce + relu ============
        if (tid < 256) {
            const int r = tid >> 7, col = tid & 127;
            float s;
            if (col < 64) {
                s = cb10[col];
#pragma unroll
                for (int kc = 0; kc < 32; ++kc) s += scratch[kc * 128 + r * 64 + col];
            } else {
                const int cc = col - 64;
                const int cell = cc >> 5, j = cc & 31;
                s = (cell ? cb12 : cb11)[j];
#pragma unroll
                for (int kc = 0; kc < 8; ++kc)
                    s += scratch[4096 + cell * 512 + kc * 64 + r * 32 + j];
            }
            hid[r][col] = fmaxf(s, 0.f);
        }
        __syncthreads();
        // ============ comp2 + z softmax ============
        if (tid < 128) {
            const int r = tid >> 6, j = tid & 63;
            float acc;
            if (j < 32) {
                acc = cb20[j];
#pragma unroll
                for (int k = 0; k < 64; ++k) acc += hid[r][k] * cw20[k * 32 + j];
            } else if (j < 48) {
                const int o = j - 32; acc = cb21[o];
#pragma unroll
                for (int k = 0; k < 32; ++k) acc += hid[r][64 + k] * cw21[k * 16 + o];
            } else {
                const int o = j - 48; acc = cb22[o];
#pragma unroll
                for (int k = 0; k < 32; ++k) acc += hid[r][96 + k] * cw22[k * 16 + o];
            }
            const float e = expf(sigf(acc));
            float v = e;
#pragma unroll
            for (int s = 32; s >= 1; s >>= 1) v += __shfl_xor(v, s);
            hz[r][192 + j] = e / v;
        }
        __syncthreads();
    }

    // ============ final MLP ============
    if (tid < 128) {
        const int r = tid >> 6, j = tid & 63;
        float acc = fb1[j];
#pragma unroll 8
        for (int k = 0; k < 64; ++k)  acc += hz[r][192 + k] * fw1[k * 64 + j];
#pragma unroll 8
        for (int k = 0; k < 192; ++k) acc += hz[r][k] * fw1[(64 + k) * 64 + j];
        hid[r][j] = fmaxf(acc, 0.f);
    }
    __syncthreads();
    if (tid < 128) {
        const int r = tid >> 6, j = tid & 63;
        float v = hid[r][j] * fw2[j];
#pragma unroll
        for (int s = 32; s >= 1; s >>= 1) v += __shfl_xor(v, s);
        if (j == 0) out[row0 + r] = v + fb2[0];
    }
}

// ---------------------------------------------------------------------------
extern "C" void kernel_launch(void* const* d_in, const int* in_sizes, int n_in,
                              void* d_out, int out_size, void* d_ws, size_t ws_size,
                              hipStream_t stream) {
    const float* x0   = (const float*)d_in[0];
    const float* x1   = (const float*)d_in[1];
    const float* x2   = (const float*)d_in[2];
    const float* W0   = (const float*)d_in[3];
    const float* U0   = (const float*)d_in[4];
    const float* V0   = (const float*)d_in[5];
    const float* b0   = (const float*)d_in[6];
    const float* W1   = (const float*)d_in[7];
    const float* U1   = (const float*)d_in[8];
    const float* V1   = (const float*)d_in[9];
    const float* b1   = (const float*)d_in[10];
    const float* W2   = (const float*)d_in[11];
    const float* U2   = (const float*)d_in[12];
    const float* V2   = (const float*)d_in[13];
    const float* b2   = (const float*)d_in[14];
    const float* aw1  = (const float*)d_in[15];
    const float* ab1  = (const float*)d_in[16];
    const float* aw2  = (const float*)d_in[17];
    const float* ab2  = (const float*)d_in[18];
    const float* cw10 = (const float*)d_in[19];
    const float* cb10 = (const float*)d_in[20];
    const float* cw20 = (const float*)d_in[21];
    const float* cb20 = (const float*)d_in[22];
    const float* cw11 = (const float*)d_in[23];
    const float* cb11 = (const float*)d_in[24];
    const float* cw21 = (const float*)d_in[25];
    const float* cb21 = (const float*)d_in[26];
    const float* cw12 = (const float*)d_in[27];
    const float* cb12 = (const float*)d_in[28];
    const float* cw22 = (const float*)d_in[29];
    const float* cb22 = (const float*)d_in[30];
    const float* fw1  = (const float*)d_in[31];
    const float* fb1  = (const float*)d_in[32];
    const float* fw2  = (const float*)d_in[33];
    const float* fb2  = (const float*)d_in[34];
    float* out = (float*)d_out;

    const size_t M = (size_t)BB * TT;   // 65536

    // workspace layout: G0 fp32, G1/G2 fp16, then fp16 weights (total ~168.7MB)
    float*  G0  = (float*)d_ws;                 // M*512 f32
    __half* G1h = (__half*)(G0 + M * 512);      // M*128 f16
    __half* G2h = G1h + M * 128;                // M*128 f16
    __half* hU0   = G2h + M * 128;   // 128*512 = 65536
    __half* hV0   = hU0 + 65536;     //  64*512 = 32768
    __half* hU1   = hV0 + 32768;     //  32*128 = 4096
    __half* hV1   = hU1 + 4096;      //  64*128 = 8192
    __half* hU2   = hV1 + 8192;      //  32*128 = 4096
    __half* hV2   = hU2 + 4096;      //  64*128 = 8192
    __half* haw1  = hV2 + 8192;      // 192*256 = 49152
    __half* haw2  = haw1 + 49152;    // 256*768 = 196608
    __half* hcw10 = haw2 + 196608;   // 512*64  = 32768
    __half* hcw11 = hcw10 + 32768;   // 128*32  = 4096
    __half* hcw12 = hcw11 + 4096;    // 128*32  = 4096

    // weight conversions
    f2h<<<(65536 + 255) / 256, 256, 0, stream>>>(U0, hU0, 65536);
    f2h<<<(32768 + 255) / 256, 256, 0, stream>>>(V0, hV0, 32768);
    f2h<<<(4096 + 255) / 256, 256, 0, stream>>>(U1, hU1, 4096);
    f2h<<<(8192 + 255) / 256, 256, 0, stream>>>(V1, hV1, 8192);
    f2h<<<(4096 + 255) / 256, 256, 0, stream>>>(U2, hU2, 4096);
    f2h<<<(8192 + 255) / 256, 256, 0, stream>>>(V2, hV2, 8192);
    f2h<<<(49152 + 255) / 256, 256, 0, stream>>>(aw1, haw1, 49152);
    f2h<<<(196608 + 255) / 256, 256, 0, stream>>>(aw2, haw2, 196608);
    f2h<<<(32768 + 255) / 256, 256, 0, stream>>>(cw10, hcw10, 32768);
    f2h<<<(4096 + 255) / 256, 256, 0, stream>>>(cw11, hcw11, 4096);
    f2h<<<(4096 + 255) / 256, 256, 0, stream>>>(cw12, hcw12, 4096);

    // G = x@W + b
    xw_gemm<float><<<dim3(512 / GT_N, M / GT_M), 256, 0, stream>>>(x0, W0, b0, G0, (int)M, 512, 300);
    xw_gemm<__half><<<dim3(128 / GT_N, M / GT_M), 256, 0, stream>>>(x1, W1, b1, G1h, (int)M, 128, 74);
    xw_gemm<__half><<<dim3(128 / GT_N, M / GT_M), 256, 0, stream>>>(x2, W2, b2, G2h, (int)M, 128, 35);

    // 128 blocks x 512 threads, 2 rows/block
    marn_rec<<<128, 512, 0, stream>>>(G0, G1h, G2h, hU0, hV0, hU1, hV1, hU2, hV2,
                                      haw1, ab1, haw2, ab2,
                                      hcw10, cb10, cw20, cb20,
                                      hcw11, cb11, cw21, cb21,
                                      hcw12, cb12, cw22, cb22,
                                      fw1, fb1, fw2, fb2, out);
}